// Round 13
// baseline (989.737 us; speedup 1.0000x reference)
//
#include <hip/hip_runtime.h>
#include <hip/hip_bf16.h>

#define HH 256
#define WW 256
#define NB 16
#define CC 64
#define NL 256
#define HWSZ (HH*WW)
#define EPSV 1e-5f
#define NYK 16     // distinct yk values: 118..133
#define YK0 118

using bf16 = __hip_bfloat16;
using short8  = __attribute__((ext_vector_type(8))) short;
using floatx4 = __attribute__((ext_vector_type(4))) float;

__device__ __forceinline__ ushort f2b(float f){
    bf16 h = __float2bfloat16(f);
    union { bf16 h; ushort u; } cv; cv.h = h; return cv.u;
}
__device__ __forceinline__ float b2fu(ushort u){
    union { unsigned int i; float f; } cv; cv.i = ((unsigned int)u) << 16; return cv.f;
}

// ---------------------------------------------------------------------------
// Weight prep. Layout per K-loop "group" g: [g][mi][lane][8ci]
//   (lane = quad*16+n16, co = mi*16+n16, ci = kc*32+quad*8+ci8)
// -> each af fragment load is ONE coalesced global_load_dwordx4.
// wkb2 (convm): 3 layers x 18 groups stored q-major (q x kc2 x p); convm
//   walks kc-major via GMAP.
// wab2 (conva): 18 enc groups + 1 tap-packed img group. Total 19 groups.
// ---------------------------------------------------------------------------
__global__ void prep_w_k(const float* __restrict__ wk, const float* __restrict__ wa,
                         ushort* __restrict__ wkb2, ushort* __restrict__ wab2)
{
    int i = blockIdx.x*256 + threadIdx.x;
    const int NWK = 3*9*64*64, NWA = 19*2048;
    if (i < NWK) {
        int ci8 = i & 7; int r = i >> 3;
        int lane = r & 63; r >>= 6;
        int mi = r & 3; r >>= 2;
        int g = r % 18; int t = r / 18;
        int q = g / 6, kc2 = (g / 3) & 1, p = g % 3;
        int quad = lane >> 4, n16 = lane & 15;
        int co = mi*16 + n16, ci = kc2*32 + quad*8 + ci8, tap = p*3 + q;
        wkb2[i] = f2b(wk[(((size_t)t*64 + co)*64 + ci)*9 + tap]);
    } else if (i < NWK + NWA) {
        int i2 = i - NWK;
        int ci8 = i2 & 7; int r = i2 >> 3;
        int lane = r & 63; r >>= 6;
        int mi = r & 3; int g = r >> 2;   // 0..18
        int quad = lane >> 4, n16 = lane & 15;
        int co = mi*16 + n16;
        float v = 0.f;
        if (g < 18) {
            int q = g/6, kc2 = (g/3)&1, p = g%3;
            int ci = kc2*32 + quad*8 + ci8, tap = p*3 + q;
            v = wa[((size_t)co*323 + 256 + ci)*9 + tap];
        } else {
            int j = quad*8 + ci8;         // tap-packed K-slot
            if (j < 27) {
                int ci = j/9, rem = j%9;  // rem = p*3+q
                v = wa[((size_t)co*323 + 320 + ci)*9 + rem];
            }
        }
        wab2[i2] = f2b(v);
    }
}

// 2-mi (wave-group-split) helpers; wbase already includes the group's
// grp*1024-short offset. All indices compile-time under unroll.
#define LDAF2(DST, G) { const ushort* bp = wbase + (size_t)(G)*2048;           \
    DST[0] = *(const short8*)(bp);                                             \
    DST[1] = *(const short8*)(bp + 512); }

#define MFMA_GRP2(AF, BF, P)                                                   \
    _Pragma("unroll") for (int mi_=0; mi_<2; mi_++) {                          \
      _Pragma("unroll") for (int ni_=0; ni_<4; ni_++)                          \
        acc[mi_][ni_] = __builtin_amdgcn_mfma_f32_16x16x32_bf16(               \
            AF[mi_], BF[ni_+(P)], acc[mi_][ni_], 0, 0, 0); }

// kc-major walk over the stored q-major group order:
// gg: kc = gg/9, q = (gg%9)/3, p = gg%3  ->  stored g = q*6 + kc*3 + p
#define GMAP(G) ((((G)%9)/3)*6 + ((G)/9)*3 + ((G)%3))

// ---------------------------------------------------------------------------
// conv0 R13: R9 structure; launch_bounds (512,6) -> 3 blocks/CU (LDS 47.5KB,
// VGPR 40 both allow it; the old (512,4) declaration was the binding cap).
// ---------------------------------------------------------------------------
__global__ __launch_bounds__(512,6) void conv0_k(
    const float* __restrict__ img, const float* __restrict__ w0,
    const float* __restrict__ bias, const float* __restrict__ gamma,
    const float* __restrict__ beta, const float* __restrict__ mean,
    const float* __restrict__ var, ushort* __restrict__ outp)
{
    __shared__ float s_i[3][18][18];
    __shared__ float s_wv[64*27];
    __shared__ float s_al[64], s_be[64];
    __shared__ ushort __align__(16) s_y[256*72];

    int tid = threadIdx.x;
    int x0 = blockIdx.x*16, y0 = blockIdx.y*16, b = blockIdx.z;
    if (tid < 64) {
        float a = gamma[tid]*rsqrtf(var[tid]+EPSV);
        s_al[tid] = a; s_be[tid] = (bias[tid]-mean[tid])*a + beta[tid];
    }
    for (int c = tid; c < 64*27; c += 512) s_wv[c] = w0[c];
    for (int c = tid; c < 3*18*18; c += 512) {
        int ci = c / 324, pp = c % 324, py = pp/18, px = pp%18;
        int gy = y0-1+py, gx = x0-1+px;
        float v = 0.f;
        if ((unsigned)gy < 256u && (unsigned)gx < 256u)
            v = img[((size_t)b*3 + ci)*HWSZ + gy*256 + gx];
        s_i[ci][py][px] = v;
    }
    __syncthreads();

    int px256 = tid & 255;                 // pixel id
    int half  = tid >> 8;                  // co half
    int ly = px256 >> 4, lx = px256 & 15;
    float xv[27];
    #pragma unroll
    for (int ci=0;ci<3;ci++)
      #pragma unroll
      for (int p=0;p<3;p++)
        #pragma unroll
        for (int q=0;q<3;q++)
            xv[ci*9+p*3+q] = s_i[ci][ly+p][lx+q];

    for (int cc=0; cc<32; cc++) {
        int co = half*32 + cc;
        float a = 0.f;
        #pragma unroll
        for (int j=0;j<27;j++) a += xv[j]*s_wv[co*27+j];
        s_y[px256*72 + co] = f2b(fmaxf(s_al[co]*a + s_be[co], 0.f));
    }
    __syncthreads();
    size_t obase = (size_t)b*HWSZ*64;
    for (int c = tid; c < 256*8; c += 512) {
        int ci8 = c & 7, px = c >> 3;
        int gy = y0 + (px>>4), gx = x0 + (px&15);
        *(uint4*)&outp[obase + (size_t)(gy*256+gx)*64 + ci8*8] =
            *(const uint4*)&s_y[px*72 + ci8*8];
    }
}

// ---------------------------------------------------------------------------
// convm R13: R10 structure; launch_bounds (512,6) -> 3 blocks/CU
// (LDS 47.6KB, VGPR ~64; cap 85 leaves headroom — watch WRITE_SIZE).
// ---------------------------------------------------------------------------
__global__ __launch_bounds__(512,6) void convm_k(
    const ushort* __restrict__ in, const ushort* __restrict__ wgt, // [18][4][64][8] prepped
    ushort* __restrict__ outp,
    const float* __restrict__ gamma, const float* __restrict__ beta,
    const float* __restrict__ mean,  const float* __restrict__ var,
    const float* __restrict__ bias,  float* __restrict__ plane)
{
    __shared__ ushort __align__(16) s_x[18*18*72];
    __shared__ float s_al[64], s_be[64];

    const int tid = threadIdx.x;
    const int x0 = blockIdx.x*16, y0 = blockIdx.y*16, b = blockIdx.z;

    if (tid < 64) {
        float a = gamma[tid]*rsqrtf(var[tid]+EPSV);
        s_al[tid] = a; s_be[tid] = (bias[tid]-mean[tid])*a + beta[tid];
    }
    const size_t ibase = (size_t)b*HWSZ*64;

    // ---- stage ch 0..31 (load + LDS write now); 1296 chunks of uint4
    {
        int c = tid;
        int ci4 = c & 3; int pp = c >> 2;
        int px = pp % 18, py = pp / 18;
        #pragma unroll
        for (int it = 0; it < 3; ++it) {
            if (c < 1296) {
                int gy = y0-1+py, gx = x0-1+px;
                uint4 v = make_uint4(0,0,0,0);
                if ((unsigned)gy < 256u && (unsigned)gx < 256u)
                    v = *(const uint4*)&in[ibase + (size_t)(gy*256+gx)*64 + ci4*8];
                *(uint4*)&s_x[pp*72 + ci4*8] = v;
            }
            c += 512; pp += 128; px += 2; py += 7;
            if (px >= 18) { px -= 18; py += 1; }
        }
    }
    // ---- issue ch 32..63 into regs; written to LDS inside the K-loop
    uint4 stgHi[3];
    {
        int c = tid;
        int ci4 = c & 3; int pp = c >> 2;
        int px = pp % 18, py = pp / 18;
        #pragma unroll
        for (int it = 0; it < 3; ++it) {
            uint4 v = make_uint4(0,0,0,0);
            if (c < 1296) {
                int gy = y0-1+py, gx = x0-1+px;
                if ((unsigned)gy < 256u && (unsigned)gx < 256u)
                    v = *(const uint4*)&in[ibase + (size_t)(gy*256+gx)*64 + 32 + ci4*8];
            }
            stgHi[it] = v;
            c += 512; pp += 128; px += 2; py += 7;
            if (px >= 18) { px -= 18; py += 1; }
        }
    }
    // publish lo half; hi global loads stay in flight across this barrier
    asm volatile("s_waitcnt lgkmcnt(0)" ::: "memory");
    __builtin_amdgcn_s_barrier();
    __builtin_amdgcn_sched_barrier(0);

    const int lane = tid & 63, wv = tid >> 6;
    const int wid = wv & 3, grp = wv >> 2;
    const int n16 = lane & 15, quad = lane >> 4;
    const ushort* wbase = wgt + (size_t)lane*8 + (size_t)grp*1024;

    floatx4 acc[2][4];
    #pragma unroll
    for (int mi=0;mi<2;mi++)
      #pragma unroll
      for (int ni=0;ni<4;ni++)
        #pragma unroll
        for (int r=0;r<4;r++) acc[mi][ni][r] = 0.f;

    short8 afA[2], afB[2], bfA[6], bfB[6];

    LDAF2(afA, GMAP(0));
    #pragma unroll
    for (int rr=0; rr<6; rr++)
        bfA[rr] = *(const short8*)&s_x[((wid*4+rr)*18 + n16)*72 + quad*8];

    #pragma unroll
    for (int gg=0; gg<18; ++gg) {
        const int p = gg % 3, jp = gg / 3;           // jp = kc*3 + q
        if (gg == 6) {
            // publish hi half (ds_written at gg==0) before any j'=3 access
            asm volatile("s_waitcnt lgkmcnt(0)" ::: "memory");
            __builtin_amdgcn_s_barrier();
            __builtin_amdgcn_sched_barrier(0);
        }
        if (gg + 1 < 18) {
            if (gg & 1) { LDAF2(afA, GMAP(gg+1)); } else { LDAF2(afB, GMAP(gg+1)); }
        }
        if (p == 0 && jp + 1 < 6) {
            const int kn = (jp+1) / 3, qn = (jp+1) % 3;
            if (jp & 1) {
                #pragma unroll
                for (int rr=0; rr<6; rr++)
                    bfA[rr] = *(const short8*)&s_x[((wid*4+rr)*18 + n16 + qn)*72 + kn*32 + quad*8];
            } else {
                #pragma unroll
                for (int rr=0; rr<6; rr++)
                    bfB[rr] = *(const short8*)&s_x[((wid*4+rr)*18 + n16 + qn)*72 + kn*32 + quad*8];
            }
        }
        if (gg == 0) {
            // write the hi half; compiler may overlap with gg=0 MFMAs
            int c = tid; int ci4 = c & 3; int pp = c >> 2;
            #pragma unroll
            for (int it = 0; it < 3; ++it) {
                if (c < 1296) *(uint4*)&s_x[pp*72 + 32 + ci4*8] = stgHi[it];
                c += 512; pp += 128;
            }
        }
        if (gg & 1) { if (jp & 1) { MFMA_GRP2(afB, bfB, p) } else { MFMA_GRP2(afB, bfA, p) } }
        else        { if (jp & 1) { MFMA_GRP2(afA, bfB, p) } else { MFMA_GRP2(afA, bfA, p) } }
    }
    __syncthreads();

    ushort* s_y = s_x;
    #pragma unroll
    for (int mi=0;mi<2;mi++)
      #pragma unroll
      for (int ni=0;ni<4;ni++) {
        int ami = grp*2 + mi;
        int px = (wid*4+ni)*16 + n16;
        int cob = ami*16 + quad*4;
        ushort u[4];
        #pragma unroll
        for (int r=0;r<4;r++) {
            float y = fmaxf(s_al[cob+r]*acc[mi][ni][r] + s_be[cob+r], 0.f);
            u[r] = f2b(y);
            if (plane && ami==0 && quad==0 && r==0)
                plane[(size_t)b*HWSZ + (y0+wid*4+ni)*256 + x0 + n16] = y;
        }
        uint2 pk; pk.x = (uint)u[0] | ((uint)u[1]<<16); pk.y = (uint)u[2] | ((uint)u[3]<<16);
        *(uint2*)&s_y[px*72 + cob] = pk;
      }
    __syncthreads();
    {
        int c = tid;
        int ci8 = c & 7, px = c >> 3;
        int gy = y0 + (px>>4), gx = x0 + (px&15);
        #pragma unroll
        for (int it = 0; it < 4; ++it) {
            *(uint4*)&outp[ibase + (size_t)(gy*256+gx)*64 + ci8*8] =
                *(const uint4*)&s_y[px*72 + ci8*8];
            px += 64; gy += 4;
        }
    }
}

// ---------------------------------------------------------------------------
// conva R13: R10 structure; launch_bounds (512,6) -> 3 blocks/CU
// (LDS 49.5KB, VGPR 64; cap 85).
// ---------------------------------------------------------------------------
__global__ __launch_bounds__(512,6) void conva_k(
    const ushort* __restrict__ enc, const float* __restrict__ img,
    const float* __restrict__ dplane, const ushort* __restrict__ wgt, // [19][4][64][8] prepped
    const float* __restrict__ gamma, const float* __restrict__ beta,
    const float* __restrict__ mean,  const float* __restrict__ var,
    const float* __restrict__ bias,
    const float* __restrict__ Tb,    // [b][64][9]
    const float* __restrict__ wf, const float* __restrict__ bfv,
    float* __restrict__ outp)
{
    __shared__ ushort __align__(16) s_x[18*18*72];
    __shared__ float s_al[64], s_be[64];
    __shared__ float s_T[64*9];
    __shared__ float s_wf[3*64];
    __shared__ float s_bf[3];

    const int tid = threadIdx.x;
    const int x0 = blockIdx.x*16, y0 = blockIdx.y*16, b = blockIdx.z;

    if (tid < 64) {
        float a = gamma[tid]*rsqrtf(var[tid]+EPSV);
        s_al[tid] = a; s_be[tid] = (bias[tid]-mean[tid])*a + beta[tid];
    }
    if (tid < 192) s_wf[tid] = wf[tid];
    if (tid < 3)   s_bf[tid] = bfv[tid];
    for (int c = tid; c < 64*9; c += 512) s_T[c] = Tb[(size_t)b*576 + c];

    const int lane = tid & 63, wv = tid >> 6;
    const int wid = wv & 3, grp = wv >> 2;
    const int n16 = lane & 15, quad = lane >> 4;
    const ushort* wbase = wgt + (size_t)lane*8 + (size_t)grp*1024;

    const size_t ibase = (size_t)b*HWSZ*64;
    // enc channels 0..63, ch0 watermark delta folded in (incremental indices)
    {
        int c = tid;
        int ci8 = c & 7; int pp = c >> 3;
        int px = pp % 18, py = pp / 18;
        #pragma unroll
        for (int it = 0; it < 6; ++it) {
            if (c < 2592) {
                int gy = y0-1+py, gx = x0-1+px;
                uint4 v = make_uint4(0,0,0,0);
                if ((unsigned)gy < 256u && (unsigned)gx < 256u) {
                    v = *(const uint4*)&enc[ibase + (size_t)(gy*256+gx)*64 + ci8*8];
                    if (ci8 == 0) {
                        float d = dplane[(size_t)b*HWSZ + gy*256 + gx];
                        ushort nb = f2b(b2fu((ushort)(v.x & 0xffffu)) + d);
                        v.x = (v.x & 0xffff0000u) | (uint)nb;
                    }
                }
                *(uint4*)&s_x[pp*72 + ci8*8] = v;
            }
            c += 512; pp += 64; px += 10; py += 3;
            if (px >= 18) { px -= 18; py += 1; }
        }
    }

    // img B-fragments in registers: slot j = quad*8+ci8 = ci*9 + p*3 + q
    short8 bimg[4];
    #pragma unroll
    for (int ni=0; ni<4; ni++) {
        short8 t;
        #pragma unroll
        for (int ci8=0; ci8<8; ci8++) {
            int j = quad*8 + ci8;
            float v = 0.f;
            if (j < 27) {
                int ci = j/9, rem = j%9, p = rem/3, q = rem%3;
                int gy = y0 + wid*4 + ni + p - 1, gx = x0 + n16 + q - 1;
                if ((unsigned)gy < 256u && (unsigned)gx < 256u)
                    v = img[((size_t)b*3 + ci)*HWSZ + gy*256 + gx];
            }
            t[ci8] = (short)f2b(v);
        }
        bimg[ni] = t;
    }
    __syncthreads();

    floatx4 acc[2][4];
    #pragma unroll
    for (int mi=0;mi<2;mi++)
      #pragma unroll
      for (int ni=0;ni<4;ni++)
        #pragma unroll
        for (int r=0;r<4;r++) acc[mi][ni][r] = 0.f;

    short8 afA[2], afB[2], bf[6];

    LDAF2(afA, 0);
    #pragma unroll
    for (int g=0; g<18; g++) {
        const int p = g % 3, j = g / 3;        // j = q*2 + kc2
        if (g & 1) { LDAF2(afA, g+1); } else { LDAF2(afB, g+1); }
        if (p == 0) {
            const int nq = j >> 1, nk = j & 1;
            #pragma unroll
            for (int rr=0; rr<6; rr++)
                bf[rr] = *(const short8*)&s_x[((wid*4+rr)*18 + n16 + nq)*72 + nk*32 + quad*8];
        }
        if (g & 1) { MFMA_GRP2(afB, bf, p) } else { MFMA_GRP2(afA, bf, p) }
    }
    // img group: weights were prefetched into afA (g=17 is odd)
    #pragma unroll
    for (int mi=0;mi<2;mi++)
      #pragma unroll
      for (int ni=0;ni<4;ni++)
        acc[mi][ni] = __builtin_amdgcn_mfma_f32_16x16x32_bf16(
            afA[mi], bimg[ni], acc[mi][ni], 0, 0, 0);

    float po[3][4];
    #pragma unroll
    for (int o=0;o<3;o++)
      #pragma unroll
      for (int ni=0;ni<4;ni++) po[o][ni] = 0.f;

    const bool interior = (x0 != 0) && (x0 != 240) && (y0 != 0) && (y0 != 240);

    #pragma unroll
    for (int mi=0;mi<2;mi++) {
        int cob = (grp*2 + mi)*16 + quad*4;
        #pragma unroll
        for (int r=0;r<4;r++) {
            int co = cob + r;
            float al = s_al[co], be = s_be[co];
            const float* t = &s_T[co*9];
            float w0f = s_wf[0*64+co], w1f = s_wf[1*64+co], w2f = s_wf[2*64+co];
            if (interior) {
                float tv = t[0];
                #pragma unroll
                for (int ni=0;ni<4;ni++) {
                    float y = fmaxf(al*(acc[mi][ni][r] + tv) + be, 0.f);
                    po[0][ni] += w0f*y; po[1][ni] += w1f*y; po[2][ni] += w2f*y;
                }
            } else {
                #pragma unroll
                for (int ni=0;ni<4;ni++) {
                    int h = y0 + wid*4 + ni, w = x0 + n16;
                    float tv = t[0];
                    if (h==0)   tv -= t[1];
                    if (h==255) tv -= t[2];
                    if (w==0)   tv -= t[3];
                    if (w==255) tv -= t[4];
                    if (h==0   && w==0)   tv += t[5];
                    if (h==0   && w==255) tv += t[6];
                    if (h==255 && w==0)   tv += t[7];
                    if (h==255 && w==255) tv += t[8];
                    float y = fmaxf(al*(acc[mi][ni][r] + tv) + be, 0.f);
                    po[0][ni] += w0f*y; po[1][ni] += w1f*y; po[2][ni] += w2f*y;
                }
            }
        }
    }
    // in-wave reduce across quads
    #pragma unroll
    for (int o=0;o<3;o++)
      #pragma unroll
      for (int ni=0;ni<4;ni++) {
        po[o][ni] += __shfl_xor(po[o][ni], 16, 64);
        po[o][ni] += __shfl_xor(po[o][ni], 32, 64);
      }
    // cross-group combine through LDS (s_x is dead now)
    __syncthreads();
    float* s_red = (float*)s_x;
    #pragma unroll
    for (int o=0;o<3;o++)
      #pragma unroll
      for (int ni=0;ni<4;ni++)
        if (grp == 1 && quad == o)
            s_red[((wid*3+o)*4+ni)*16 + n16] = po[o][ni];
    __syncthreads();
    #pragma unroll
    for (int o=0;o<3;o++)
      #pragma unroll
      for (int ni=0;ni<4;ni++)
        if (grp == 0 && quad == o) {
            int h = y0 + wid*4 + ni, w = x0 + n16;
            outp[((size_t)b*3 + o)*HWSZ + h*256 + w] =
                po[o][ni] + s_red[((wid*3+o)*4+ni)*16 + n16] + s_bf[o];
        }
}

// ---------------------------------------------------------------------------
// msgterm R12 (kept): wave shuffle reduction, single barrier.
// ---------------------------------------------------------------------------
__global__ __launch_bounds__(256) void msgterm_k(const float* __restrict__ msg,
                                                 const float* __restrict__ wa,
                                                 float* __restrict__ Tbuf)
{
    __shared__ float s_p[4][9];
    int b = blockIdx.x, o = blockIdx.y, l = threadIdx.x;
    int lane = l & 63, wvi = l >> 6;
    float m = msg[b*NL + l];
    float wv[9];
    #pragma unroll
    for (int t=0;t<9;t++) wv[t] = wa[((size_t)o*323 + l)*9 + t] * m;
    float comp[9];
    comp[0] = wv[0]+wv[1]+wv[2]+wv[3]+wv[4]+wv[5]+wv[6]+wv[7]+wv[8];
    comp[1] = wv[0]+wv[1]+wv[2];
    comp[2] = wv[6]+wv[7]+wv[8];
    comp[3] = wv[0]+wv[3]+wv[6];
    comp[4] = wv[2]+wv[5]+wv[8];
    comp[5] = wv[0]; comp[6]=wv[2]; comp[7]=wv[6]; comp[8]=wv[8];
    #pragma unroll
    for (int cpi=0;cpi<9;cpi++){
        #pragma unroll
        for (int off=32; off>0; off>>=1)
            comp[cpi] += __shfl_xor(comp[cpi], off, 64);
    }
    if (lane == 0) {
        #pragma unroll
        for (int cpi=0;cpi<9;cpi++) s_p[wvi][cpi] = comp[cpi];
    }
    __syncthreads();
    if (l < 9)
        Tbuf[((size_t)b*CC+o)*9+l] = s_p[0][l]+s_p[1][l]+s_p[2][l]+s_p[3][l];
}

__global__ void build_idx_k(int* __restrict__ idx)
{
    if (threadIdx.x==0 && blockIdx.x==0) {
        int n=0;
        for (int i=-10;i<=10;i++)
            for (int j=-10;j<=10;j++) {
                if (n>=NL) return;
                if (i*i+j*j<=100) { idx[2*n]=128+i; idx[2*n+1]=128+j; n++; }
            }
    }
}

// ---------------------------------------------------------------------------
// Separable watermark DFT pipeline (R12 2-part split, kept).
// Cbuf/Sbuf layout: [b][t][part][2][256] floats.
// ---------------------------------------------------------------------------
__global__ __launch_bounds__(256) void colA_k(const float* __restrict__ plane,
                                              float* __restrict__ Cbuf)
{
    __shared__ float twc[256], tws[256];
    int t = blockIdx.x, part = blockIdx.y, b = blockIdx.z, w = threadIdx.x;
    float sv, cv;
    __sincosf(6.283185307179586f * (float)w / 256.0f, &sv, &cv);
    twc[w]=cv; tws[w]=sv;
    __syncthreads();
    int yk = YK0 + t;
    const float* pb = &plane[(size_t)b*HWSZ];
    int h0 = part*128;
    int m = (h0*yk) & 255;
    float fr=0.f, fi=0.f;
    for (int h=h0; h<h0+128; h++) {
        float xv = pb[h*256 + w];
        fr += xv*twc[m];
        fi -= xv*tws[m];
        m = (m + yk) & 255;
    }
    float* Cb = &Cbuf[((size_t)((b*NYK + t)*2 + part)*2)*256];
    Cb[w]       = fr;
    Cb[256 + w] = fi;
}

__global__ __launch_bounds__(256) void freqB_k(const float* __restrict__ Cbuf,
                                               const float* __restrict__ msg,
                                               const int* __restrict__ idx,
                                               float* __restrict__ D)
{
    __shared__ float twc[256], tws[256];
    __shared__ float sfr[4], sfi[4];
    int k = blockIdx.x, b = blockIdx.y, w = threadIdx.x;
    float sv, cv;
    __sincosf(6.283185307179586f * (float)w / 256.0f, &sv, &cv);
    twc[w]=cv; tws[w]=sv;
    __syncthreads();
    int yk = idx[2*k], xk = idx[2*k+1];
    int t = yk - YK0;
    const float* Cb = &Cbuf[((size_t)((b*NYK + t)*2)*2)*256];
    float Cr = Cb[w]       + Cb[512 + w];
    float Ci = Cb[256 + w] + Cb[768 + w];
    int ang = (xk*w) & 255;
    float cx = twc[ang], sx = tws[ang];
    float fr = Cr*cx + Ci*sx;
    float fi = Ci*cx - Cr*sx;
    #pragma unroll
    for (int off=32; off>0; off>>=1) {
        fr += __shfl_xor(fr, off, 64);
        fi += __shfl_xor(fi, off, 64);
    }
    if ((w & 63) == 0) { sfr[w>>6] = fr; sfi[w>>6] = fi; }
    __syncthreads();
    if (w == 0) {
        float FR = sfr[0]+sfr[1]+sfr[2]+sfr[3];
        float FI = sfi[0]+sfi[1]+sfi[2]+sfi[3];
        float mv = msg[b*NL + k];
        D[((size_t)b*NL + k)*2 + 0] = mv - FR;
        D[((size_t)b*NL + k)*2 + 1] = mv - FI;
    }
}

__global__ __launch_bounds__(256) void rowC_k(const int* __restrict__ idx,
                                              const float* __restrict__ D,
                                              float* __restrict__ Sbuf)
{
    __shared__ float twc[256], tws[256], dr[256], di[256];
    __shared__ int iy[256], ix[256];
    int t = blockIdx.x, part = blockIdx.y, b = blockIdx.z, w = threadIdx.x;
    float sv, cv;
    __sincosf(6.283185307179586f * (float)w / 256.0f, &sv, &cv);
    twc[w]=cv; tws[w]=sv;
    dr[w] = D[((size_t)b*NL + w)*2+0];
    di[w] = D[((size_t)b*NL + w)*2+1];
    iy[w] = idx[2*w]; ix[w] = idx[2*w+1];
    __syncthreads();
    int yk = YK0 + t;
    float Sr=0.f, Si=0.f;
    for (int k=part*128; k<part*128+128; k++) {
        if (iy[k] != yk) continue;           // wave-uniform branch
        int ang = (ix[k]*w) & 255;
        float c = twc[ang], s = tws[ang];
        Sr += dr[k]*c - di[k]*s;
        Si += dr[k]*s + di[k]*c;
    }
    float* Sb = &Sbuf[((size_t)((b*NYK + t)*2 + part)*2)*256];
    Sb[w]       = Sr;
    Sb[256 + w] = Si;
}

__global__ __launch_bounds__(256) void applyD_k(const float* __restrict__ Sbuf,
                                                float* __restrict__ dplane)
{
    __shared__ float twc[256], tws[256];
    int h = blockIdx.x, b = blockIdx.y, w = threadIdx.x;
    float sv, cv;
    __sincosf(6.283185307179586f * (float)w / 256.0f, &sv, &cv);
    twc[w]=cv; tws[w]=sv;
    __syncthreads();
    float acc = 0.f;
    #pragma unroll
    for (int t=0;t<NYK;t++) {
        int yk = YK0 + t;
        int ang = (yk*h) & 255;              // wave-uniform
        float cy = twc[ang], sy = tws[ang];
        const float* Sb = &Sbuf[((size_t)((b*NYK + t)*2)*2)*256];
        float Sr = Sb[w]       + Sb[512 + w];
        float Si = Sb[256 + w] + Sb[768 + w];
        acc += cy*Sr - sy*Si;
    }
    dplane[(size_t)b*HWSZ + h*256 + w] = acc * (1.0f/65536.0f);
}

// ---------------------------------------------------------------------------
extern "C" void kernel_launch(void* const* d_in, const int* in_sizes, int n_in,
                              void* d_out, int out_size, void* d_ws, size_t ws_size,
                              hipStream_t stream)
{
    const float* image = (const float*)d_in[0];
    const float* msg   = (const float*)d_in[1];
    const float* w0    = (const float*)d_in[2];
    const float* b0    = (const float*)d_in[3];
    const float* g0    = (const float*)d_in[4];
    const float* be0   = (const float*)d_in[5];
    const float* m0    = (const float*)d_in[6];
    const float* v0    = (const float*)d_in[7];
    const float* wk    = (const float*)d_in[8];
    const float* bk    = (const float*)d_in[9];
    const float* gk    = (const float*)d_in[10];
    const float* bek   = (const float*)d_in[11];
    const float* mk    = (const float*)d_in[12];
    const float* vk    = (const float*)d_in[13];
    const float* wa    = (const float*)d_in[14];
    const float* ba    = (const float*)d_in[15];
    const float* ga    = (const float*)d_in[16];
    const float* bea   = (const float*)d_in[17];
    const float* ma    = (const float*)d_in[18];
    const float* va    = (const float*)d_in[19];
    const float* wf    = (const float*)d_in[20];
    const float* bfv   = (const float*)d_in[21];
    float* out = (float*)d_out;

    // Layout (13 MB header): Cbuf/Sbuf doubled for the 2-part DFT split.
    char* base = (char*)d_ws;
    int*    idx    = (int*)base;                              // 2 KB
    float*  Dbuf   = (float*)(base + (4<<10));                // 32 KB
    float*  Tbuf   = (float*)(base + (40<<10));               // 36 KB
    ushort* wkb2   = (ushort*)(base + (128<<10));             // 216 KB
    ushort* wab2   = (ushort*)(base + (384<<10));             // 76 KB (19 groups)
    float*  Cbuf   = (float*)(base + (512<<10));              // <=1 MB
    float*  Sbuf   = (float*)(base + (1536<<10));             // <=1 MB
    float*  plane  = (float*)(base + ((size_t)3<<20));        // 4.2 MB
    float*  dplane = (float*)(base + ((size_t)8<<20));        // 4.2 MB
    ushort* bufA   = (ushort*)(base + ((size_t)13<<20));

    const size_t perB = (size_t)HWSZ*64*2*2;  // 16.8 MB: both bf16 buffers / batch
    int chunk = 1;
    for (int c = NB; c >= 1; c >>= 1)
        if (((size_t)13<<20) + (size_t)c*perB <= ws_size) { chunk = c; break; }
    ushort* bufB = bufA + (size_t)chunk*HWSZ*64;

    build_idx_k<<<1,64,0,stream>>>(idx);
    msgterm_k<<<dim3(NB,CC),256,0,stream>>>(msg, wa, Tbuf);
    int prep_n = (3*9*64*64 + 19*2048 + 255)/256;
    prep_w_k<<<prep_n,256,0,stream>>>(wk, wa, wkb2, wab2);

    const size_t WL = (size_t)9*64*64;  // one layer of wkb2

    for (int cs = 0; cs < NB; cs += chunk) {
        dim3 g(16,16,chunk);
        const float* img_c = image + (size_t)cs*3*HWSZ;

        conv0_k<<<g,512,0,stream>>>(img_c, w0, b0, g0, be0, m0, v0, bufA);
        convm_k<<<g,512,0,stream>>>(bufA, wkb2 + 0*WL, bufB,
            gk+0*CC, bek+0*CC, mk+0*CC, vk+0*CC, bk+0*CC, nullptr);
        convm_k<<<g,512,0,stream>>>(bufB, wkb2 + 1*WL, bufA,
            gk+1*CC, bek+1*CC, mk+1*CC, vk+1*CC, bk+1*CC, nullptr);
        convm_k<<<g,512,0,stream>>>(bufA, wkb2 + 2*WL, bufB,
            gk+2*CC, bek+2*CC, mk+2*CC, vk+2*CC, bk+2*CC, plane);

        // separable watermark DFT (forward + inverse), 2-part split
        colA_k<<<dim3(NYK,2,chunk),256,0,stream>>>(plane, Cbuf);
        freqB_k<<<dim3(NL,chunk),256,0,stream>>>(Cbuf, msg + (size_t)cs*NL, idx, Dbuf);
        rowC_k<<<dim3(NYK,2,chunk),256,0,stream>>>(idx, Dbuf, Sbuf);
        applyD_k<<<dim3(HH,chunk),256,0,stream>>>(Sbuf, dplane);

        conva_k<<<g,512,0,stream>>>(bufB, img_c, dplane, wab2,
            ga, bea, ma, va, ba, Tbuf + (size_t)cs*CC*9, wf, bfv,
            out + (size_t)cs*3*HWSZ);
    }
}

// Round 14
// 735.610 us; speedup vs baseline: 1.3455x; 1.3455x over previous
//
#include <hip/hip_runtime.h>
#include <hip/hip_bf16.h>

#define HH 256
#define WW 256
#define NB 16
#define CC 64
#define NL 256
#define HWSZ (HH*WW)
#define EPSV 1e-5f
#define NYK 16     // distinct yk values: 118..133
#define YK0 118

using bf16 = __hip_bfloat16;
using short8  = __attribute__((ext_vector_type(8))) short;
using floatx4 = __attribute__((ext_vector_type(4))) float;

__device__ __forceinline__ ushort f2b(float f){
    bf16 h = __float2bfloat16(f);
    union { bf16 h; ushort u; } cv; cv.h = h; return cv.u;
}
__device__ __forceinline__ float b2fu(ushort u){
    union { unsigned int i; float f; } cv; cv.i = ((unsigned int)u) << 16; return cv.f;
}

// ---------------------------------------------------------------------------
// Weight prep. Layout per K-loop "group" g: [g][mi][lane][8ci]
//   (lane = quad*16+n16, co = mi*16+n16, ci = kc*32+quad*8+ci8)
// -> each af fragment load is ONE coalesced global_load_dwordx4.
// wkb2 (convm): 3 layers x 18 groups stored q-major (q x kc2 x p); convm
//   walks kc-major via GMAP.
// wab2 (conva): 18 enc groups + 1 tap-packed img group. Total 19 groups.
// ---------------------------------------------------------------------------
__global__ void prep_w_k(const float* __restrict__ wk, const float* __restrict__ wa,
                         ushort* __restrict__ wkb2, ushort* __restrict__ wab2)
{
    int i = blockIdx.x*256 + threadIdx.x;
    const int NWK = 3*9*64*64, NWA = 19*2048;
    if (i < NWK) {
        int ci8 = i & 7; int r = i >> 3;
        int lane = r & 63; r >>= 6;
        int mi = r & 3; r >>= 2;
        int g = r % 18; int t = r / 18;
        int q = g / 6, kc2 = (g / 3) & 1, p = g % 3;
        int quad = lane >> 4, n16 = lane & 15;
        int co = mi*16 + n16, ci = kc2*32 + quad*8 + ci8, tap = p*3 + q;
        wkb2[i] = f2b(wk[(((size_t)t*64 + co)*64 + ci)*9 + tap]);
    } else if (i < NWK + NWA) {
        int i2 = i - NWK;
        int ci8 = i2 & 7; int r = i2 >> 3;
        int lane = r & 63; r >>= 6;
        int mi = r & 3; int g = r >> 2;   // 0..18
        int quad = lane >> 4, n16 = lane & 15;
        int co = mi*16 + n16;
        float v = 0.f;
        if (g < 18) {
            int q = g/6, kc2 = (g/3)&1, p = g%3;
            int ci = kc2*32 + quad*8 + ci8, tap = p*3 + q;
            v = wa[((size_t)co*323 + 256 + ci)*9 + tap];
        } else {
            int j = quad*8 + ci8;         // tap-packed K-slot
            if (j < 27) {
                int ci = j/9, rem = j%9;  // rem = p*3+q
                v = wa[((size_t)co*323 + 320 + ci)*9 + rem];
            }
        }
        wab2[i2] = f2b(v);
    }
}

// 2-mi (wave-group-split) helpers; wbase already includes the group's
// grp*1024-short offset. All indices compile-time under unroll.
#define LDAF2(DST, G) { const ushort* bp = wbase + (size_t)(G)*2048;           \
    DST[0] = *(const short8*)(bp);                                             \
    DST[1] = *(const short8*)(bp + 512); }

#define MFMA_GRP2(AF, BF, P)                                                   \
    _Pragma("unroll") for (int mi_=0; mi_<2; mi_++) {                          \
      _Pragma("unroll") for (int ni_=0; ni_<4; ni_++)                          \
        acc[mi_][ni_] = __builtin_amdgcn_mfma_f32_16x16x32_bf16(               \
            AF[mi_], BF[ni_+(P)], acc[mi_][ni_], 0, 0, 0); }

// kc-major walk over the stored q-major group order:
// gg: kc = gg/9, q = (gg%9)/3, p = gg%3  ->  stored g = q*6 + kc*3 + p
#define GMAP(G) ((((G)%9)/3)*6 + ((G)/9)*3 + ((G)%3))

// ---------------------------------------------------------------------------
// conv0 R9 (kept): 512 threads, output-channel split across thread halves.
// launch_bounds (512,4): measured best; (512,6) spills (R13).
// ---------------------------------------------------------------------------
__global__ __launch_bounds__(512,4) void conv0_k(
    const float* __restrict__ img, const float* __restrict__ w0,
    const float* __restrict__ bias, const float* __restrict__ gamma,
    const float* __restrict__ beta, const float* __restrict__ mean,
    const float* __restrict__ var, ushort* __restrict__ outp)
{
    __shared__ float s_i[3][18][18];
    __shared__ float s_wv[64*27];
    __shared__ float s_al[64], s_be[64];
    __shared__ ushort __align__(16) s_y[256*72];

    int tid = threadIdx.x;
    int x0 = blockIdx.x*16, y0 = blockIdx.y*16, b = blockIdx.z;
    if (tid < 64) {
        float a = gamma[tid]*rsqrtf(var[tid]+EPSV);
        s_al[tid] = a; s_be[tid] = (bias[tid]-mean[tid])*a + beta[tid];
    }
    for (int c = tid; c < 64*27; c += 512) s_wv[c] = w0[c];
    for (int c = tid; c < 3*18*18; c += 512) {
        int ci = c / 324, pp = c % 324, py = pp/18, px = pp%18;
        int gy = y0-1+py, gx = x0-1+px;
        float v = 0.f;
        if ((unsigned)gy < 256u && (unsigned)gx < 256u)
            v = img[((size_t)b*3 + ci)*HWSZ + gy*256 + gx];
        s_i[ci][py][px] = v;
    }
    __syncthreads();

    int px256 = tid & 255;                 // pixel id
    int half  = tid >> 8;                  // co half
    int ly = px256 >> 4, lx = px256 & 15;
    float xv[27];
    #pragma unroll
    for (int ci=0;ci<3;ci++)
      #pragma unroll
      for (int p=0;p<3;p++)
        #pragma unroll
        for (int q=0;q<3;q++)
            xv[ci*9+p*3+q] = s_i[ci][ly+p][lx+q];

    for (int cc=0; cc<32; cc++) {
        int co = half*32 + cc;
        float a = 0.f;
        #pragma unroll
        for (int j=0;j<27;j++) a += xv[j]*s_wv[co*27+j];
        s_y[px256*72 + co] = f2b(fmaxf(s_al[co]*a + s_be[co], 0.f));
    }
    __syncthreads();
    size_t obase = (size_t)b*HWSZ*64;
    for (int c = tid; c < 256*8; c += 512) {
        int ci8 = c & 7, px = c >> 3;
        int gy = y0 + (px>>4), gx = x0 + (px&15);
        *(uint4*)&outp[obase + (size_t)(gy*256+gx)*64 + ci8*8] =
            *(const uint4*)&s_y[px*72 + ci8*8];
    }
}

// ---------------------------------------------------------------------------
// convm R10 (kept): 512-thread co-split + split-K staging pipeline.
// launch_bounds (512,4): measured best; (512,6) spills (R13).
// ---------------------------------------------------------------------------
__global__ __launch_bounds__(512,4) void convm_k(
    const ushort* __restrict__ in, const ushort* __restrict__ wgt, // [18][4][64][8] prepped
    ushort* __restrict__ outp,
    const float* __restrict__ gamma, const float* __restrict__ beta,
    const float* __restrict__ mean,  const float* __restrict__ var,
    const float* __restrict__ bias,  float* __restrict__ plane)
{
    __shared__ ushort __align__(16) s_x[18*18*72];
    __shared__ float s_al[64], s_be[64];

    const int tid = threadIdx.x;
    const int x0 = blockIdx.x*16, y0 = blockIdx.y*16, b = blockIdx.z;

    if (tid < 64) {
        float a = gamma[tid]*rsqrtf(var[tid]+EPSV);
        s_al[tid] = a; s_be[tid] = (bias[tid]-mean[tid])*a + beta[tid];
    }
    const size_t ibase = (size_t)b*HWSZ*64;

    // ---- stage ch 0..31 (load + LDS write now); 1296 chunks of uint4
    {
        int c = tid;
        int ci4 = c & 3; int pp = c >> 2;
        int px = pp % 18, py = pp / 18;
        #pragma unroll
        for (int it = 0; it < 3; ++it) {
            if (c < 1296) {
                int gy = y0-1+py, gx = x0-1+px;
                uint4 v = make_uint4(0,0,0,0);
                if ((unsigned)gy < 256u && (unsigned)gx < 256u)
                    v = *(const uint4*)&in[ibase + (size_t)(gy*256+gx)*64 + ci4*8];
                *(uint4*)&s_x[pp*72 + ci4*8] = v;
            }
            c += 512; pp += 128; px += 2; py += 7;
            if (px >= 18) { px -= 18; py += 1; }
        }
    }
    // ---- issue ch 32..63 into regs; written to LDS inside the K-loop
    uint4 stgHi[3];
    {
        int c = tid;
        int ci4 = c & 3; int pp = c >> 2;
        int px = pp % 18, py = pp / 18;
        #pragma unroll
        for (int it = 0; it < 3; ++it) {
            uint4 v = make_uint4(0,0,0,0);
            if (c < 1296) {
                int gy = y0-1+py, gx = x0-1+px;
                if ((unsigned)gy < 256u && (unsigned)gx < 256u)
                    v = *(const uint4*)&in[ibase + (size_t)(gy*256+gx)*64 + 32 + ci4*8];
            }
            stgHi[it] = v;
            c += 512; pp += 128; px += 2; py += 7;
            if (px >= 18) { px -= 18; py += 1; }
        }
    }
    // publish lo half; hi global loads stay in flight across this barrier
    asm volatile("s_waitcnt lgkmcnt(0)" ::: "memory");
    __builtin_amdgcn_s_barrier();
    __builtin_amdgcn_sched_barrier(0);

    const int lane = tid & 63, wv = tid >> 6;
    const int wid = wv & 3, grp = wv >> 2;
    const int n16 = lane & 15, quad = lane >> 4;
    const ushort* wbase = wgt + (size_t)lane*8 + (size_t)grp*1024;

    floatx4 acc[2][4];
    #pragma unroll
    for (int mi=0;mi<2;mi++)
      #pragma unroll
      for (int ni=0;ni<4;ni++)
        #pragma unroll
        for (int r=0;r<4;r++) acc[mi][ni][r] = 0.f;

    short8 afA[2], afB[2], bfA[6], bfB[6];

    LDAF2(afA, GMAP(0));
    #pragma unroll
    for (int rr=0; rr<6; rr++)
        bfA[rr] = *(const short8*)&s_x[((wid*4+rr)*18 + n16)*72 + quad*8];

    #pragma unroll
    for (int gg=0; gg<18; ++gg) {
        const int p = gg % 3, jp = gg / 3;           // jp = kc*3 + q
        if (gg == 6) {
            // publish hi half (ds_written at gg==0) before any j'=3 access
            asm volatile("s_waitcnt lgkmcnt(0)" ::: "memory");
            __builtin_amdgcn_s_barrier();
            __builtin_amdgcn_sched_barrier(0);
        }
        if (gg + 1 < 18) {
            if (gg & 1) { LDAF2(afA, GMAP(gg+1)); } else { LDAF2(afB, GMAP(gg+1)); }
        }
        if (p == 0 && jp + 1 < 6) {
            const int kn = (jp+1) / 3, qn = (jp+1) % 3;
            if (jp & 1) {
                #pragma unroll
                for (int rr=0; rr<6; rr++)
                    bfA[rr] = *(const short8*)&s_x[((wid*4+rr)*18 + n16 + qn)*72 + kn*32 + quad*8];
            } else {
                #pragma unroll
                for (int rr=0; rr<6; rr++)
                    bfB[rr] = *(const short8*)&s_x[((wid*4+rr)*18 + n16 + qn)*72 + kn*32 + quad*8];
            }
        }
        if (gg == 0) {
            // write the hi half; compiler may overlap with gg=0 MFMAs
            int c = tid; int ci4 = c & 3; int pp = c >> 2;
            #pragma unroll
            for (int it = 0; it < 3; ++it) {
                if (c < 1296) *(uint4*)&s_x[pp*72 + 32 + ci4*8] = stgHi[it];
                c += 512; pp += 128;
            }
        }
        if (gg & 1) { if (jp & 1) { MFMA_GRP2(afB, bfB, p) } else { MFMA_GRP2(afB, bfA, p) } }
        else        { if (jp & 1) { MFMA_GRP2(afA, bfB, p) } else { MFMA_GRP2(afA, bfA, p) } }
    }
    __syncthreads();

    ushort* s_y = s_x;
    #pragma unroll
    for (int mi=0;mi<2;mi++)
      #pragma unroll
      for (int ni=0;ni<4;ni++) {
        int ami = grp*2 + mi;
        int px = (wid*4+ni)*16 + n16;
        int cob = ami*16 + quad*4;
        ushort u[4];
        #pragma unroll
        for (int r=0;r<4;r++) {
            float y = fmaxf(s_al[cob+r]*acc[mi][ni][r] + s_be[cob+r], 0.f);
            u[r] = f2b(y);
            if (plane && ami==0 && quad==0 && r==0)
                plane[(size_t)b*HWSZ + (y0+wid*4+ni)*256 + x0 + n16] = y;
        }
        uint2 pk; pk.x = (uint)u[0] | ((uint)u[1]<<16); pk.y = (uint)u[2] | ((uint)u[3]<<16);
        *(uint2*)&s_y[px*72 + cob] = pk;
      }
    __syncthreads();
    {
        int c = tid;
        int ci8 = c & 7, px = c >> 3;
        int gy = y0 + (px>>4), gx = x0 + (px&15);
        #pragma unroll
        for (int it = 0; it < 4; ++it) {
            *(uint4*)&outp[ibase + (size_t)(gy*256+gx)*64 + ci8*8] =
                *(const uint4*)&s_y[px*72 + ci8*8];
            px += 64; gy += 4;
        }
    }
}

// ---------------------------------------------------------------------------
// conva R10 (kept): co-split, tap-packed img group, interior fast-path.
// launch_bounds (512,4): measured best; (512,6) spills (R13).
// ---------------------------------------------------------------------------
__global__ __launch_bounds__(512,4) void conva_k(
    const ushort* __restrict__ enc, const float* __restrict__ img,
    const float* __restrict__ dplane, const ushort* __restrict__ wgt, // [19][4][64][8] prepped
    const float* __restrict__ gamma, const float* __restrict__ beta,
    const float* __restrict__ mean,  const float* __restrict__ var,
    const float* __restrict__ bias,
    const float* __restrict__ Tb,    // [b][64][9]
    const float* __restrict__ wf, const float* __restrict__ bfv,
    float* __restrict__ outp)
{
    __shared__ ushort __align__(16) s_x[18*18*72];
    __shared__ float s_al[64], s_be[64];
    __shared__ float s_T[64*9];
    __shared__ float s_wf[3*64];
    __shared__ float s_bf[3];

    const int tid = threadIdx.x;
    const int x0 = blockIdx.x*16, y0 = blockIdx.y*16, b = blockIdx.z;

    if (tid < 64) {
        float a = gamma[tid]*rsqrtf(var[tid]+EPSV);
        s_al[tid] = a; s_be[tid] = (bias[tid]-mean[tid])*a + beta[tid];
    }
    if (tid < 192) s_wf[tid] = wf[tid];
    if (tid < 3)   s_bf[tid] = bfv[tid];
    for (int c = tid; c < 64*9; c += 512) s_T[c] = Tb[(size_t)b*576 + c];

    const int lane = tid & 63, wv = tid >> 6;
    const int wid = wv & 3, grp = wv >> 2;
    const int n16 = lane & 15, quad = lane >> 4;
    const ushort* wbase = wgt + (size_t)lane*8 + (size_t)grp*1024;

    const size_t ibase = (size_t)b*HWSZ*64;
    // enc channels 0..63, ch0 watermark delta folded in (incremental indices)
    {
        int c = tid;
        int ci8 = c & 7; int pp = c >> 3;
        int px = pp % 18, py = pp / 18;
        #pragma unroll
        for (int it = 0; it < 6; ++it) {
            if (c < 2592) {
                int gy = y0-1+py, gx = x0-1+px;
                uint4 v = make_uint4(0,0,0,0);
                if ((unsigned)gy < 256u && (unsigned)gx < 256u) {
                    v = *(const uint4*)&enc[ibase + (size_t)(gy*256+gx)*64 + ci8*8];
                    if (ci8 == 0) {
                        float d = dplane[(size_t)b*HWSZ + gy*256 + gx];
                        ushort nb = f2b(b2fu((ushort)(v.x & 0xffffu)) + d);
                        v.x = (v.x & 0xffff0000u) | (uint)nb;
                    }
                }
                *(uint4*)&s_x[pp*72 + ci8*8] = v;
            }
            c += 512; pp += 64; px += 10; py += 3;
            if (px >= 18) { px -= 18; py += 1; }
        }
    }

    // img B-fragments in registers: slot j = quad*8+ci8 = ci*9 + p*3 + q
    short8 bimg[4];
    #pragma unroll
    for (int ni=0; ni<4; ni++) {
        short8 t;
        #pragma unroll
        for (int ci8=0; ci8<8; ci8++) {
            int j = quad*8 + ci8;
            float v = 0.f;
            if (j < 27) {
                int ci = j/9, rem = j%9, p = rem/3, q = rem%3;
                int gy = y0 + wid*4 + ni + p - 1, gx = x0 + n16 + q - 1;
                if ((unsigned)gy < 256u && (unsigned)gx < 256u)
                    v = img[((size_t)b*3 + ci)*HWSZ + gy*256 + gx];
            }
            t[ci8] = (short)f2b(v);
        }
        bimg[ni] = t;
    }
    __syncthreads();

    floatx4 acc[2][4];
    #pragma unroll
    for (int mi=0;mi<2;mi++)
      #pragma unroll
      for (int ni=0;ni<4;ni++)
        #pragma unroll
        for (int r=0;r<4;r++) acc[mi][ni][r] = 0.f;

    short8 afA[2], afB[2], bf[6];

    LDAF2(afA, 0);
    #pragma unroll
    for (int g=0; g<18; g++) {
        const int p = g % 3, j = g / 3;        // j = q*2 + kc2
        if (g & 1) { LDAF2(afA, g+1); } else { LDAF2(afB, g+1); }
        if (p == 0) {
            const int nq = j >> 1, nk = j & 1;
            #pragma unroll
            for (int rr=0; rr<6; rr++)
                bf[rr] = *(const short8*)&s_x[((wid*4+rr)*18 + n16 + nq)*72 + nk*32 + quad*8];
        }
        if (g & 1) { MFMA_GRP2(afB, bf, p) } else { MFMA_GRP2(afA, bf, p) }
    }
    // img group: weights were prefetched into afA (g=17 is odd)
    #pragma unroll
    for (int mi=0;mi<2;mi++)
      #pragma unroll
      for (int ni=0;ni<4;ni++)
        acc[mi][ni] = __builtin_amdgcn_mfma_f32_16x16x32_bf16(
            afA[mi], bimg[ni], acc[mi][ni], 0, 0, 0);

    float po[3][4];
    #pragma unroll
    for (int o=0;o<3;o++)
      #pragma unroll
      for (int ni=0;ni<4;ni++) po[o][ni] = 0.f;

    const bool interior = (x0 != 0) && (x0 != 240) && (y0 != 0) && (y0 != 240);

    #pragma unroll
    for (int mi=0;mi<2;mi++) {
        int cob = (grp*2 + mi)*16 + quad*4;
        #pragma unroll
        for (int r=0;r<4;r++) {
            int co = cob + r;
            float al = s_al[co], be = s_be[co];
            const float* t = &s_T[co*9];
            float w0f = s_wf[0*64+co], w1f = s_wf[1*64+co], w2f = s_wf[2*64+co];
            if (interior) {
                float tv = t[0];
                #pragma unroll
                for (int ni=0;ni<4;ni++) {
                    float y = fmaxf(al*(acc[mi][ni][r] + tv) + be, 0.f);
                    po[0][ni] += w0f*y; po[1][ni] += w1f*y; po[2][ni] += w2f*y;
                }
            } else {
                #pragma unroll
                for (int ni=0;ni<4;ni++) {
                    int h = y0 + wid*4 + ni, w = x0 + n16;
                    float tv = t[0];
                    if (h==0)   tv -= t[1];
                    if (h==255) tv -= t[2];
                    if (w==0)   tv -= t[3];
                    if (w==255) tv -= t[4];
                    if (h==0   && w==0)   tv += t[5];
                    if (h==0   && w==255) tv += t[6];
                    if (h==255 && w==0)   tv += t[7];
                    if (h==255 && w==255) tv += t[8];
                    float y = fmaxf(al*(acc[mi][ni][r] + tv) + be, 0.f);
                    po[0][ni] += w0f*y; po[1][ni] += w1f*y; po[2][ni] += w2f*y;
                }
            }
        }
    }
    // in-wave reduce across quads
    #pragma unroll
    for (int o=0;o<3;o++)
      #pragma unroll
      for (int ni=0;ni<4;ni++) {
        po[o][ni] += __shfl_xor(po[o][ni], 16, 64);
        po[o][ni] += __shfl_xor(po[o][ni], 32, 64);
      }
    // cross-group combine through LDS (s_x is dead now)
    __syncthreads();
    float* s_red = (float*)s_x;
    #pragma unroll
    for (int o=0;o<3;o++)
      #pragma unroll
      for (int ni=0;ni<4;ni++)
        if (grp == 1 && quad == o)
            s_red[((wid*3+o)*4+ni)*16 + n16] = po[o][ni];
    __syncthreads();
    #pragma unroll
    for (int o=0;o<3;o++)
      #pragma unroll
      for (int ni=0;ni<4;ni++)
        if (grp == 0 && quad == o) {
            int h = y0 + wid*4 + ni, w = x0 + n16;
            outp[((size_t)b*3 + o)*HWSZ + h*256 + w] =
                po[o][ni] + s_red[((wid*3+o)*4+ni)*16 + n16] + s_bf[o];
        }
}

// ---------------------------------------------------------------------------
// msgterm R12 (kept): wave shuffle reduction, single barrier.
// ---------------------------------------------------------------------------
__global__ __launch_bounds__(256) void msgterm_k(const float* __restrict__ msg,
                                                 const float* __restrict__ wa,
                                                 float* __restrict__ Tbuf)
{
    __shared__ float s_p[4][9];
    int b = blockIdx.x, o = blockIdx.y, l = threadIdx.x;
    int lane = l & 63, wvi = l >> 6;
    float m = msg[b*NL + l];
    float wv[9];
    #pragma unroll
    for (int t=0;t<9;t++) wv[t] = wa[((size_t)o*323 + l)*9 + t] * m;
    float comp[9];
    comp[0] = wv[0]+wv[1]+wv[2]+wv[3]+wv[4]+wv[5]+wv[6]+wv[7]+wv[8];
    comp[1] = wv[0]+wv[1]+wv[2];
    comp[2] = wv[6]+wv[7]+wv[8];
    comp[3] = wv[0]+wv[3]+wv[6];
    comp[4] = wv[2]+wv[5]+wv[8];
    comp[5] = wv[0]; comp[6]=wv[2]; comp[7]=wv[6]; comp[8]=wv[8];
    #pragma unroll
    for (int cpi=0;cpi<9;cpi++){
        #pragma unroll
        for (int off=32; off>0; off>>=1)
            comp[cpi] += __shfl_xor(comp[cpi], off, 64);
    }
    if (lane == 0) {
        #pragma unroll
        for (int cpi=0;cpi<9;cpi++) s_p[wvi][cpi] = comp[cpi];
    }
    __syncthreads();
    if (l < 9)
        Tbuf[((size_t)b*CC+o)*9+l] = s_p[0][l]+s_p[1][l]+s_p[2][l]+s_p[3][l];
}

__global__ void build_idx_k(int* __restrict__ idx)
{
    if (threadIdx.x==0 && blockIdx.x==0) {
        int n=0;
        for (int i=-10;i<=10;i++)
            for (int j=-10;j<=10;j++) {
                if (n>=NL) return;
                if (i*i+j*j<=100) { idx[2*n]=128+i; idx[2*n+1]=128+j; n++; }
            }
    }
}

// ---------------------------------------------------------------------------
// Separable watermark DFT pipeline (R12 2-part split, kept).
// Cbuf/Sbuf layout: [b][t][part][2][256] floats.
// ---------------------------------------------------------------------------
__global__ __launch_bounds__(256) void colA_k(const float* __restrict__ plane,
                                              float* __restrict__ Cbuf)
{
    __shared__ float twc[256], tws[256];
    int t = blockIdx.x, part = blockIdx.y, b = blockIdx.z, w = threadIdx.x;
    float sv, cv;
    __sincosf(6.283185307179586f * (float)w / 256.0f, &sv, &cv);
    twc[w]=cv; tws[w]=sv;
    __syncthreads();
    int yk = YK0 + t;
    const float* pb = &plane[(size_t)b*HWSZ];
    int h0 = part*128;
    int m = (h0*yk) & 255;
    float fr=0.f, fi=0.f;
    for (int h=h0; h<h0+128; h++) {
        float xv = pb[h*256 + w];
        fr += xv*twc[m];
        fi -= xv*tws[m];
        m = (m + yk) & 255;
    }
    float* Cb = &Cbuf[((size_t)((b*NYK + t)*2 + part)*2)*256];
    Cb[w]       = fr;
    Cb[256 + w] = fi;
}

__global__ __launch_bounds__(256) void freqB_k(const float* __restrict__ Cbuf,
                                               const float* __restrict__ msg,
                                               const int* __restrict__ idx,
                                               float* __restrict__ D)
{
    __shared__ float twc[256], tws[256];
    __shared__ float sfr[4], sfi[4];
    int k = blockIdx.x, b = blockIdx.y, w = threadIdx.x;
    float sv, cv;
    __sincosf(6.283185307179586f * (float)w / 256.0f, &sv, &cv);
    twc[w]=cv; tws[w]=sv;
    __syncthreads();
    int yk = idx[2*k], xk = idx[2*k+1];
    int t = yk - YK0;
    const float* Cb = &Cbuf[((size_t)((b*NYK + t)*2)*2)*256];
    float Cr = Cb[w]       + Cb[512 + w];
    float Ci = Cb[256 + w] + Cb[768 + w];
    int ang = (xk*w) & 255;
    float cx = twc[ang], sx = tws[ang];
    float fr = Cr*cx + Ci*sx;
    float fi = Ci*cx - Cr*sx;
    #pragma unroll
    for (int off=32; off>0; off>>=1) {
        fr += __shfl_xor(fr, off, 64);
        fi += __shfl_xor(fi, off, 64);
    }
    if ((w & 63) == 0) { sfr[w>>6] = fr; sfi[w>>6] = fi; }
    __syncthreads();
    if (w == 0) {
        float FR = sfr[0]+sfr[1]+sfr[2]+sfr[3];
        float FI = sfi[0]+sfi[1]+sfi[2]+sfi[3];
        float mv = msg[b*NL + k];
        D[((size_t)b*NL + k)*2 + 0] = mv - FR;
        D[((size_t)b*NL + k)*2 + 1] = mv - FI;
    }
}

__global__ __launch_bounds__(256) void rowC_k(const int* __restrict__ idx,
                                              const float* __restrict__ D,
                                              float* __restrict__ Sbuf)
{
    __shared__ float twc[256], tws[256], dr[256], di[256];
    __shared__ int iy[256], ix[256];
    int t = blockIdx.x, part = blockIdx.y, b = blockIdx.z, w = threadIdx.x;
    float sv, cv;
    __sincosf(6.283185307179586f * (float)w / 256.0f, &sv, &cv);
    twc[w]=cv; tws[w]=sv;
    dr[w] = D[((size_t)b*NL + w)*2+0];
    di[w] = D[((size_t)b*NL + w)*2+1];
    iy[w] = idx[2*w]; ix[w] = idx[2*w+1];
    __syncthreads();
    int yk = YK0 + t;
    float Sr=0.f, Si=0.f;
    for (int k=part*128; k<part*128+128; k++) {
        if (iy[k] != yk) continue;           // wave-uniform branch
        int ang = (ix[k]*w) & 255;
        float c = twc[ang], s = tws[ang];
        Sr += dr[k]*c - di[k]*s;
        Si += dr[k]*s + di[k]*c;
    }
    float* Sb = &Sbuf[((size_t)((b*NYK + t)*2 + part)*2)*256];
    Sb[w]       = Sr;
    Sb[256 + w] = Si;
}

__global__ __launch_bounds__(256) void applyD_k(const float* __restrict__ Sbuf,
                                                float* __restrict__ dplane)
{
    __shared__ float twc[256], tws[256];
    int h = blockIdx.x, b = blockIdx.y, w = threadIdx.x;
    float sv, cv;
    __sincosf(6.283185307179586f * (float)w / 256.0f, &sv, &cv);
    twc[w]=cv; tws[w]=sv;
    __syncthreads();
    float acc = 0.f;
    #pragma unroll
    for (int t=0;t<NYK;t++) {
        int yk = YK0 + t;
        int ang = (yk*h) & 255;              // wave-uniform
        float cy = twc[ang], sy = tws[ang];
        const float* Sb = &Sbuf[((size_t)((b*NYK + t)*2)*2)*256];
        float Sr = Sb[w]       + Sb[512 + w];
        float Si = Sb[256 + w] + Sb[768 + w];
        acc += cy*Sr - sy*Si;
    }
    dplane[(size_t)b*HWSZ + h*256 + w] = acc * (1.0f/65536.0f);
}

// ---------------------------------------------------------------------------
extern "C" void kernel_launch(void* const* d_in, const int* in_sizes, int n_in,
                              void* d_out, int out_size, void* d_ws, size_t ws_size,
                              hipStream_t stream)
{
    const float* image = (const float*)d_in[0];
    const float* msg   = (const float*)d_in[1];
    const float* w0    = (const float*)d_in[2];
    const float* b0    = (const float*)d_in[3];
    const float* g0    = (const float*)d_in[4];
    const float* be0   = (const float*)d_in[5];
    const float* m0    = (const float*)d_in[6];
    const float* v0    = (const float*)d_in[7];
    const float* wk    = (const float*)d_in[8];
    const float* bk    = (const float*)d_in[9];
    const float* gk    = (const float*)d_in[10];
    const float* bek   = (const float*)d_in[11];
    const float* mk    = (const float*)d_in[12];
    const float* vk    = (const float*)d_in[13];
    const float* wa    = (const float*)d_in[14];
    const float* ba    = (const float*)d_in[15];
    const float* ga    = (const float*)d_in[16];
    const float* bea   = (const float*)d_in[17];
    const float* ma    = (const float*)d_in[18];
    const float* va    = (const float*)d_in[19];
    const float* wf    = (const float*)d_in[20];
    const float* bfv   = (const float*)d_in[21];
    float* out = (float*)d_out;

    // Layout (13 MB header): Cbuf/Sbuf doubled for the 2-part DFT split.
    char* base = (char*)d_ws;
    int*    idx    = (int*)base;                              // 2 KB
    float*  Dbuf   = (float*)(base + (4<<10));                // 32 KB
    float*  Tbuf   = (float*)(base + (40<<10));               // 36 KB
    ushort* wkb2   = (ushort*)(base + (128<<10));             // 216 KB
    ushort* wab2   = (ushort*)(base + (384<<10));             // 76 KB (19 groups)
    float*  Cbuf   = (float*)(base + (512<<10));              // <=1 MB
    float*  Sbuf   = (float*)(base + (1536<<10));             // <=1 MB
    float*  plane  = (float*)(base + ((size_t)3<<20));        // 4.2 MB
    float*  dplane = (float*)(base + ((size_t)8<<20));        // 4.2 MB
    ushort* bufA   = (ushort*)(base + ((size_t)13<<20));

    const size_t perB = (size_t)HWSZ*64*2*2;  // 16.8 MB: both bf16 buffers / batch
    int chunk = 1;
    for (int c = NB; c >= 1; c >>= 1)
        if (((size_t)13<<20) + (size_t)c*perB <= ws_size) { chunk = c; break; }
    ushort* bufB = bufA + (size_t)chunk*HWSZ*64;

    build_idx_k<<<1,64,0,stream>>>(idx);
    msgterm_k<<<dim3(NB,CC),256,0,stream>>>(msg, wa, Tbuf);
    int prep_n = (3*9*64*64 + 19*2048 + 255)/256;
    prep_w_k<<<prep_n,256,0,stream>>>(wk, wa, wkb2, wab2);

    const size_t WL = (size_t)9*64*64;  // one layer of wkb2

    for (int cs = 0; cs < NB; cs += chunk) {
        dim3 g(16,16,chunk);
        const float* img_c = image + (size_t)cs*3*HWSZ;

        conv0_k<<<g,512,0,stream>>>(img_c, w0, b0, g0, be0, m0, v0, bufA);
        convm_k<<<g,512,0,stream>>>(bufA, wkb2 + 0*WL, bufB,
            gk+0*CC, bek+0*CC, mk+0*CC, vk+0*CC, bk+0*CC, nullptr);
        convm_k<<<g,512,0,stream>>>(bufB, wkb2 + 1*WL, bufA,
            gk+1*CC, bek+1*CC, mk+1*CC, vk+1*CC, bk+1*CC, nullptr);
        convm_k<<<g,512,0,stream>>>(bufA, wkb2 + 2*WL, bufB,
            gk+2*CC, bek+2*CC, mk+2*CC, vk+2*CC, bk+2*CC, plane);

        // separable watermark DFT (forward + inverse), 2-part split
        colA_k<<<dim3(NYK,2,chunk),256,0,stream>>>(plane, Cbuf);
        freqB_k<<<dim3(NL,chunk),256,0,stream>>>(Cbuf, msg + (size_t)cs*NL, idx, Dbuf);
        rowC_k<<<dim3(NYK,2,chunk),256,0,stream>>>(idx, Dbuf, Sbuf);
        applyD_k<<<dim3(HH,chunk),256,0,stream>>>(Sbuf, dplane);

        conva_k<<<g,512,0,stream>>>(bufB, img_c, dplane, wab2,
            ga, bea, ma, va, ba, Tbuf + (size_t)cs*CC*9, wf, bfv,
            out + (size_t)cs*3*HWSZ);
    }
}